// Round 1
// baseline (435.632 us; speedup 1.0000x reference)
//
#include <hip/hip_runtime.h>
#include <hip/hip_bf16.h>

#define BB 64
#define SS 8192
#define DD 128
#define NCHUNK 32   // chunks per batch
#define CHROWS 256  // rows per chunk
#define NT 4        // 64-row tiles per chunk

typedef __attribute__((ext_vector_type(8))) short bf16x8;
typedef __attribute__((ext_vector_type(4))) float f32x4;

// swizzled slot within a (w,kk) 128-slot region; 8-byte units
#define SWZ(c, qd) ((qd) * 16 + ((c) ^ (2 * (qd))))

__device__ __forceinline__ unsigned pk2(float x, float y) {
    __hip_bfloat162 h = __float22bfloat162_rn(make_float2(x, y));
    union { __hip_bfloat162 h2; unsigned u; } cv;
    cv.h2 = h;
    return cv.u;
}

__device__ __forceinline__ float bflo(unsigned p) { return __uint_as_float(p << 16); }
__device__ __forceinline__ float bfhi(unsigned p) { return __uint_as_float(p & 0xffff0000u); }

__device__ __forceinline__ float tanh_fast(float x) {
    float e = __expf(2.f * x);
    return 1.f - 2.f / (e + 1.f);
}

// ---------------- K1: q = tanh(input @ W_dec^T + b_dec)
__global__ void qproj_kernel(const float* __restrict__ input,
                             const float* __restrict__ W_dec,
                             const float* __restrict__ b_dec,
                             float* __restrict__ q) {
    __shared__ float xin[DD];
    const int b = blockIdx.x, d = threadIdx.x;  // 128 threads
    xin[d] = input[b * DD + d];
    __syncthreads();
    const float4* wrow = (const float4*)(W_dec + (size_t)d * DD);
    float acc = 0.f;
#pragma unroll
    for (int k4 = 0; k4 < DD / 4; k4++) {
        float4 w = wrow[k4];
        float4 x = ((const float4*)xin)[k4];
        acc += w.x * x.x + w.y * x.y + w.z * x.z + w.w * x.w;
    }
    q[b * DD + d] = tanh_fast(acc + b_dec[d]);
}

// ---------------- K2: fused scores + online softmax + weighted ctx sum
// Fragment-direct global loads: each lane loads its MFMA A-fragment
// (row = wv*16+col, k = kk*32+quad*8+j) straight from HBM, converts to bf16
// in-register, and the weighted-context sum reuses the same registers.
// No ctx LDS tile, 2 syncs/tile.
__global__ __launch_bounds__(256, 3) void score_fused_kernel(
    const float* __restrict__ ctx,
    const float* __restrict__ W_enc,
    const float* __restrict__ b_enc,
    const float* __restrict__ q,
    float* __restrict__ scores,
    float* __restrict__ wcp,   // [2048][128]
    float* __restrict__ Mp,    // [2048]
    float* __restrict__ Tp) {  // [2048]
    __shared__ __align__(16) short Wl[16384];  // 32 KB fragment-order W_enc
    __shared__ float sw[64];
    __shared__ float red[512];

    const int t = threadIdx.x;

    // ---- stage W_enc: region (nt*4+kk), slot SWZ(col,qd), halves h=0/1
    const float4* W4 = (const float4*)W_enc;
    for (int c2 = t; c2 < 2048; c2 += 256) {
        int row = c2 >> 4, kc = c2 & 15;
        float4 f0 = W4[row * 32 + kc * 2];
        float4 f1 = W4[row * 32 + kc * 2 + 1];
        int nt = row >> 4, colw = row & 15, kk = kc >> 2, qd = kc & 3;
        int a8 = (nt * 4 + kk) * 128 + SWZ(colw, qd) * 2;
        uint4 u;
        u.x = pk2(f0.x, f0.y); u.y = pk2(f0.z, f0.w);
        u.z = pk2(f1.x, f1.y); u.w = pk2(f1.z, f1.w);
        *(uint4*)&Wl[a8 * 4] = u;
    }

    const int wv = t >> 6, lane = t & 63;
    const int col = lane & 15, quad = lane >> 4;
    const int b = blockIdx.x >> 5;
    const int chunk = blockIdx.x & 31;

    float qv[8], bv[8];
#pragma unroll
    for (int nt = 0; nt < 8; nt++) {
        qv[nt] = q[b * DD + nt * 16 + col];
        bv[nt] = b_enc[nt * 16 + col];
    }

    // fragment-order global base: row = b*SS + chunk*256 + wv*16 + col,
    // dim offset quad*8 (float4 index quad*2), +kk*8 f4 per k-group
    const float4* cbase = (const float4*)ctx
        + ((size_t)b * SS + (size_t)chunk * CHROWS + wv * 16 + col) * (DD / 4)
        + quad * 2;

    float4 S[8];
#pragma unroll
    for (int kk = 0; kk < 4; kk++) {
        S[kk * 2]     = cbase[kk * 8];
        S[kk * 2 + 1] = cbase[kk * 8 + 1];
    }

    union FU { bf16x8 v; unsigned u[4]; };
    FU af[4];
    auto cvt_frags = [&]() {
#pragma unroll
        for (int kk = 0; kk < 4; kk++) {
            float4 f0 = S[kk * 2], f1 = S[kk * 2 + 1];
            af[kk].u[0] = pk2(f0.x, f0.y);
            af[kk].u[1] = pk2(f0.z, f0.w);
            af[kk].u[2] = pk2(f1.x, f1.y);
            af[kk].u[3] = pk2(f1.z, f1.w);
        }
    };
    cvt_frags();  // tile 0 fragments ready
    __syncthreads();  // Wl ready

    float Mrun = -INFINITY, Trun = 0.f;
    float acc32[32];
#pragma unroll
    for (int i = 0; i < 32; i++) acc32[i] = 0.f;

    for (int it = 0; it < NT; ++it) {
        // prefetch next tile into staging regs (in flight across whole tile)
        if (it < NT - 1) {
            const float4* nb = cbase + (size_t)(it + 1) * (64 * DD / 4);
#pragma unroll
            for (int kk = 0; kk < 4; kk++) {
                S[kk * 2]     = nb[kk * 8];
                S[kk * 2 + 1] = nb[kk * 8 + 1];
            }
        }

        // ---- MFMA + tanh-dot epilogue, two halves of 4 n-tiles (VGPR diet)
        float vr[4] = {0.f, 0.f, 0.f, 0.f};
#pragma unroll
        for (int h = 0; h < 2; h++) {
            f32x4 acc[4];
#pragma unroll
            for (int nt = 0; nt < 4; nt++) {
                int ntg = h * 4 + nt;
                f32x4 c = {0.f, 0.f, 0.f, 0.f};
#pragma unroll
                for (int kk = 0; kk < 4; kk++) {
                    int a8 = (ntg * 4 + kk) * 128 + SWZ(col, quad) * 2;
                    bf16x8 bf = *(const bf16x8*)&Wl[a8 * 4];
                    c = __builtin_amdgcn_mfma_f32_16x16x32_bf16(af[kk].v, bf, c, 0, 0, 0);
                }
                acc[nt] = c;
            }
#pragma unroll
            for (int r = 0; r < 4; r++) {
#pragma unroll
                for (int nt = 0; nt < 4; nt++) {
                    int ntg = h * 4 + nt;
                    vr[r] += tanh_fast(acc[nt][r] + bv[ntg]) * qv[ntg];
                }
            }
        }
#pragma unroll
        for (int r = 0; r < 4; r++) {
            float v = vr[r];
            v += __shfl_xor(v, 1);
            v += __shfl_xor(v, 2);
            v += __shfl_xor(v, 4);
            v += __shfl_xor(v, 8);
            if (col == 0) {
                int lrow = wv * 16 + quad * 4 + r;
                sw[lrow] = v;
                scores[(size_t)b * SS + (size_t)chunk * CHROWS + it * 64 + lrow] = v;
            }
        }
        __syncthreads();  // sw visible to all waves

        // ---- per-wave (redundant) online softmax over this tile's 64 rows
        float sv = sw[lane];
        float m = sv;
#pragma unroll
        for (int off = 1; off < 64; off <<= 1) m = fmaxf(m, __shfl_xor(m, off));
        float Mnew = fmaxf(Mrun, m);
        float alpha = __expf(Mrun - Mnew);
        float wlane = __expf(sv - Mnew);
        float ts = wlane;
#pragma unroll
        for (int off = 1; off < 64; off <<= 1) ts += __shfl_xor(ts, off);
        Trun = Trun * alpha + ts;
        Mrun = Mnew;

        // ---- weighted ctx accumulation straight from fragment registers
        float wi = __shfl(wlane, wv * 16 + col);  // weight of this thread's row
#pragma unroll
        for (int kk = 0; kk < 4; kk++) {
#pragma unroll
            for (int w = 0; w < 4; w++) {
                unsigned pw = af[kk].u[w];
                acc32[kk * 8 + 2 * w]     = acc32[kk * 8 + 2 * w] * alpha + wi * bflo(pw);
                acc32[kk * 8 + 2 * w + 1] = acc32[kk * 8 + 2 * w + 1] * alpha + wi * bfhi(pw);
            }
        }

        __syncthreads();  // all waves done reading sw

        if (it < NT - 1) cvt_frags();  // convert prefetched tile -> fragments
    }

    // ---- reduce acc32 over the 16 col-lanes; dims d = kk*32 + quad*8 + j
#pragma unroll
    for (int i = 0; i < 32; i++) {
        acc32[i] += __shfl_xor(acc32[i], 1);
        acc32[i] += __shfl_xor(acc32[i], 2);
        acc32[i] += __shfl_xor(acc32[i], 4);
        acc32[i] += __shfl_xor(acc32[i], 8);
    }
    if (col == 0) {
#pragma unroll
        for (int kk = 0; kk < 4; kk++)
#pragma unroll
            for (int j = 0; j < 8; j++)
                red[wv * 128 + kk * 32 + quad * 8 + j] = acc32[kk * 8 + j];
    }
    __syncthreads();
    if (t < 128) {
        float s = red[t] + red[128 + t] + red[256 + t] + red[384 + t];
        wcp[(size_t)blockIdx.x * DD + t] = s;
    }
    if (t == 0) {
        Mp[blockIdx.x] = Mrun;
        Tp[blockIdx.x] = Trun;
    }
}

// ---------------- K3: combine 32 per-block partials per batch + fused out proj
__global__ void combine_out_kernel(const float* __restrict__ wcp,
                                   const float* __restrict__ Mp,
                                   const float* __restrict__ Tp,
                                   const float* __restrict__ q,
                                   const float* __restrict__ W_out,
                                   float* __restrict__ h,
                                   float* __restrict__ Ms,
                                   float* __restrict__ Tinv) {
    __shared__ float cat[2 * DD];
    const int b = blockIdx.x, d = threadIdx.x;  // 128 threads
    float M = -INFINITY;
#pragma unroll
    for (int j = 0; j < NCHUNK; j++) M = fmaxf(M, Mp[b * NCHUNK + j]);
    float T = 0.f, acc = 0.f;
#pragma unroll
    for (int j = 0; j < NCHUNK; j++) {
        float e = __expf(Mp[b * NCHUNK + j] - M);
        T += Tp[b * NCHUNK + j] * e;
        acc += wcp[(size_t)(b * NCHUNK + j) * DD + d] * e;
    }
    float ti = 1.f / T;
    cat[d] = acc * ti;          // weighted_context
    cat[DD + d] = q[b * DD + d];
    if (d == 0) { Ms[b] = M; Tinv[b] = ti; }
    __syncthreads();
    const float4* wrow = (const float4*)(W_out + (size_t)d * 2 * DD);
    float a2 = 0.f;
#pragma unroll
    for (int k4 = 0; k4 < 2 * DD / 4; k4++) {
        float4 w = wrow[k4];
        float4 x = ((const float4*)cat)[k4];
        a2 += w.x * x.x + w.y * x.y + w.z * x.z + w.w * x.w;
    }
    h[b * DD + d] = tanh_fast(a2);
}

// ---------------- K4: attn = exp(scores - M)/T
__global__ __launch_bounds__(512) void attnfin_kernel(const float* __restrict__ scores,
                                                      const float* __restrict__ Ms,
                                                      const float* __restrict__ Tinv,
                                                      float* __restrict__ attn) {
    const int b = blockIdx.x >> 2, seg = blockIdx.x & 3;
    const float M = Ms[b], ti = Tinv[b];
    const float4* s4 = (const float4*)(scores + (size_t)b * SS) + seg * 512;
    float4* a4 = (float4*)(attn + (size_t)b * SS) + seg * 512;
    float4 v = s4[threadIdx.x];
    v.x = __expf(v.x - M) * ti;
    v.y = __expf(v.y - M) * ti;
    v.z = __expf(v.z - M) * ti;
    v.w = __expf(v.w - M) * ti;
    a4[threadIdx.x] = v;
}

extern "C" void kernel_launch(void* const* d_in, const int* in_sizes, int n_in,
                              void* d_out, int out_size, void* d_ws, size_t ws_size,
                              hipStream_t stream) {
    const float* input = (const float*)d_in[0];
    const float* ctx   = (const float*)d_in[1];
    const float* W_enc = (const float*)d_in[2];
    const float* b_enc = (const float*)d_in[3];
    const float* W_dec = (const float*)d_in[4];
    const float* b_dec = (const float*)d_in[5];
    const float* W_out = (const float*)d_in[6];

    float* h    = (float*)d_out;            // [B, D]
    float* attn = (float*)d_out + BB * DD;  // [B, S]

    float* ws     = (float*)d_ws;
    float* q      = ws;                       // 8192
    float* scores = ws + 8192;                // 524288 raw scores
    float* wcp    = scores + 524288;          // 2048*128 partials
    float* Mp     = wcp + 2048 * DD;          // 2048
    float* Tp     = Mp + 2048;                // 2048
    float* Ms     = Tp + 2048;                // 64
    float* Tinv   = Ms + 64;                  // 64

    qproj_kernel<<<BB, DD, 0, stream>>>(input, W_dec, b_dec, q);
    score_fused_kernel<<<BB * NCHUNK, 256, 0, stream>>>(ctx, W_enc, b_enc, q,
                                                        scores, wcp, Mp, Tp);
    combine_out_kernel<<<BB, DD, 0, stream>>>(wcp, Mp, Tp, q, W_out, h, Ms, Tinv);
    attnfin_kernel<<<BB * 4, 512, 0, stream>>>(scores, Ms, Tinv, attn);
}

// Round 2
// 400.346 us; speedup vs baseline: 1.0881x; 1.0881x over previous
//
#include <hip/hip_runtime.h>
#include <hip/hip_bf16.h>

#define BB 64
#define SS 8192
#define DD 128
#define NCHUNK 8    // chunks per batch
#define CHROWS 1024 // rows per chunk
#define NTILE 16    // 64-row tiles per chunk

typedef __attribute__((ext_vector_type(8))) short bf16x8;
typedef __attribute__((ext_vector_type(4))) float f32x4;

// swizzled slot within a (w,kk) 128-slot region; 8-byte units
#define SWZ(c, qd) ((qd) * 16 + ((c) ^ (2 * (qd))))

__device__ __forceinline__ unsigned pk2(float x, float y) {
    __hip_bfloat162 h = __float22bfloat162_rn(make_float2(x, y));
    union { __hip_bfloat162 h2; unsigned u; } cv;
    cv.h2 = h;
    return cv.u;
}

__device__ __forceinline__ float bflo(unsigned p) { return __uint_as_float(p << 16); }
__device__ __forceinline__ float bfhi(unsigned p) { return __uint_as_float(p & 0xffff0000u); }

__device__ __forceinline__ float tanh_fast(float x) {
    float e = __expf(2.f * x);
    return 1.f - 2.f / (e + 1.f);
}

// ---------------- K1: q = tanh(input @ W_dec^T + b_dec)
__global__ void qproj_kernel(const float* __restrict__ input,
                             const float* __restrict__ W_dec,
                             const float* __restrict__ b_dec,
                             float* __restrict__ q) {
    __shared__ float xin[DD];
    const int b = blockIdx.x, d = threadIdx.x;  // 128 threads
    xin[d] = input[b * DD + d];
    __syncthreads();
    const float4* wrow = (const float4*)(W_dec + (size_t)d * DD);
    float acc = 0.f;
#pragma unroll
    for (int k4 = 0; k4 < DD / 4; k4++) {
        float4 w = wrow[k4];
        float4 x = ((const float4*)xin)[k4];
        acc += w.x * x.x + w.y * x.y + w.z * x.z + w.w * x.w;
    }
    q[b * DD + d] = tanh_fast(acc + b_dec[d]);
}

// ---------------- K2: fused scores + online softmax + weighted ctx sum
// LDS-staged, coalesced loads (proven 420.9us structure), now:
//  - grid 512 = 2 blocks/CU, ALL co-resident (no 256-block tail round)
//  - double-buffered ctx tile -> 2 syncs/tile instead of 3
__global__ __launch_bounds__(256, 2) void score_fused_kernel(
    const float* __restrict__ ctx,
    const float* __restrict__ W_enc,
    const float* __restrict__ b_enc,
    const float* __restrict__ q,
    float* __restrict__ scores,
    float* __restrict__ wcp,   // [512][128]
    float* __restrict__ Mp,    // [512]
    float* __restrict__ Tp) {  // [512]
    __shared__ __align__(16) short Wl[16384];     // 32 KB fragment-order W_enc
    __shared__ __align__(16) short Cl[2][8192];   // 2 x 16 KB swizzled bf16 ctx tile
    __shared__ float sw[64];
    __shared__ float4 red[256];

    const int t = threadIdx.x;

    // ---- stage W_enc: region (nt*4+kk), slot SWZ(col,qd), halves h=0/1
    const float4* W4 = (const float4*)W_enc;
    for (int c2 = t; c2 < 2048; c2 += 256) {
        int row = c2 >> 4, kc = c2 & 15;
        float4 f0 = W4[row * 32 + kc * 2];
        float4 f1 = W4[row * 32 + kc * 2 + 1];
        int nt = row >> 4, colw = row & 15, kk = kc >> 2, qd = kc & 3;
        int a8 = (nt * 4 + kk) * 128 + SWZ(colw, qd) * 2;
        uint4 u;
        u.x = pk2(f0.x, f0.y); u.y = pk2(f0.z, f0.w);
        u.z = pk2(f1.x, f1.y); u.w = pk2(f1.z, f1.w);
        *(uint4*)&Wl[a8 * 4] = u;
    }

    const int wv = t >> 6, lane = t & 63;
    const int col = lane & 15, quad = lane >> 4;
    const int b = blockIdx.x >> 3;
    const int chunk = blockIdx.x & 7;

    // per-thread piece coords for pack / weighted-sum
    const int u = t & 31, rg = t >> 5;
    const int ukk = u >> 3, uqd = (u >> 1) & 3, uh = u & 1;

    float qv[8], bv[8];
#pragma unroll
    for (int nt = 0; nt < 8; nt++) {
        qv[nt] = q[b * DD + nt * 16 + col];
        bv[nt] = b_enc[nt * 16 + col];
    }

    const float4* base = (const float4*)(ctx + ((size_t)b * SS + (size_t)chunk * CHROWS) * DD);

    float4 R[8];
    // pack R -> Cl[buf] at this thread's 8 (row, piece) slots
    auto pack_tile = [&](int buf) {
#pragma unroll
        for (int i = 0; i < 8; i++) {
            int row = rg + 8 * i, w = row >> 4, c = row & 15;
            int a8 = (w * 4 + ukk) * 128 + SWZ(c, uqd) * 2 + uh;
            uint2 pk;
            pk.x = pk2(R[i].x, R[i].y);
            pk.y = pk2(R[i].z, R[i].w);
            *(uint2*)&Cl[buf][a8 * 4] = pk;
        }
    };

    // prologue: tile 0
#pragma unroll
    for (int i = 0; i < 8; i++) R[i] = base[t + 256 * i];
    pack_tile(0);
    __syncthreads();

    float Mrun = -INFINITY, Trun = 0.f;
    float4 acc4 = {0.f, 0.f, 0.f, 0.f};

    for (int it = 0; it < NTILE; ++it) {
        const int cur = it & 1;
        // prefetch next tile into the single register staging buffer
        if (it < NTILE - 1) {
            const float4* tb = base + (size_t)(it + 1) * 2048;
#pragma unroll
            for (int i = 0; i < 8; i++) R[i] = tb[t + 256 * i];
        }

        // ---- MFMA from swizzled Cl[cur] / Wl
        bf16x8 a[4];
#pragma unroll
        for (int kk = 0; kk < 4; kk++) {
            int a8 = (wv * 4 + kk) * 128 + SWZ(col, quad) * 2;
            a[kk] = *(const bf16x8*)&Cl[cur][a8 * 4];
        }
        f32x4 acc[8];
#pragma unroll
        for (int nt = 0; nt < 8; nt++) {
            f32x4 c = {0.f, 0.f, 0.f, 0.f};
#pragma unroll
            for (int kk = 0; kk < 4; kk++) {
                int a8 = (nt * 4 + kk) * 128 + SWZ(col, quad) * 2;
                bf16x8 bf = *(const bf16x8*)&Wl[a8 * 4];
                c = __builtin_amdgcn_mfma_f32_16x16x32_bf16(a[kk], bf, c, 0, 0, 0);
            }
            acc[nt] = c;
        }

        // ---- epilogue: tanh, dot q, col-reduce, write sw + raw scores
#pragma unroll
        for (int r = 0; r < 4; r++) {
            float v = 0.f;
#pragma unroll
            for (int nt = 0; nt < 8; nt++)
                v += tanh_fast(acc[nt][r] + bv[nt]) * qv[nt];
            v += __shfl_xor(v, 1);
            v += __shfl_xor(v, 2);
            v += __shfl_xor(v, 4);
            v += __shfl_xor(v, 8);
            if (col == 0) {
                int lrow = wv * 16 + quad * 4 + r;
                sw[lrow] = v;
                scores[(size_t)b * SS + (size_t)chunk * CHROWS + it * 64 + lrow] = v;
            }
        }
        __syncthreads();  // sync A: sw visible (Cl[cur] frag reads also done)

        // ---- per-wave (redundant) online softmax over this tile's 64 rows
        float sv = sw[lane];
        float m = sv;
#pragma unroll
        for (int off = 1; off < 64; off <<= 1) m = fmaxf(m, __shfl_xor(m, off));
        float Mnew = fmaxf(Mrun, m);
        float alpha = __expf(Mrun - Mnew);
        float wlane = __expf(sv - Mnew);
        float ts = wlane;
#pragma unroll
        for (int off = 1; off < 64; off <<= 1) ts += __shfl_xor(ts, off);
        Trun = Trun * alpha + ts;
        Mrun = Mnew;

        // ---- weighted ctx accumulation from the bf16 LDS tile (buffer cur)
        acc4.x *= alpha; acc4.y *= alpha; acc4.z *= alpha; acc4.w *= alpha;
#pragma unroll
        for (int i = 0; i < 8; i++) {
            int row = rg + 8 * i, w = row >> 4, c = row & 15;
            int a8 = (w * 4 + ukk) * 128 + SWZ(c, uqd) * 2 + uh;
            uint2 pk = *(const uint2*)&Cl[cur][a8 * 4];
            float wi = __shfl(wlane, row);
            acc4.x += wi * bflo(pk.x);
            acc4.y += wi * bfhi(pk.x);
            acc4.z += wi * bflo(pk.y);
            acc4.w += wi * bfhi(pk.y);
        }

        // pack the prefetched tile into the OTHER buffer (no reader hazard)
        if (it < NTILE - 1) pack_tile(cur ^ 1);

        __syncthreads();  // sync B: Cl[cur^1] ready; sw reads done
    }

    // ---- block reduce: thread t holds dims [4u,4u+4) over row-group rg
    red[t] = acc4;
    __syncthreads();
    if (t < 32) {
        float4 s = red[t];
#pragma unroll
        for (int k = 1; k < 8; k++) {
            float4 p = red[t + 32 * k];
            s.x += p.x; s.y += p.y; s.z += p.z; s.w += p.w;
        }
        *(float4*)&wcp[(size_t)blockIdx.x * DD + 4 * t] = s;
    }
    if (t == 0) {
        Mp[blockIdx.x] = Mrun;
        Tp[blockIdx.x] = Trun;
    }
}

// ---------------- K3: combine 8 per-block partials per batch + fused out proj
__global__ void combine_out_kernel(const float* __restrict__ wcp,
                                   const float* __restrict__ Mp,
                                   const float* __restrict__ Tp,
                                   const float* __restrict__ q,
                                   const float* __restrict__ W_out,
                                   float* __restrict__ h,
                                   float* __restrict__ Ms,
                                   float* __restrict__ Tinv) {
    __shared__ float cat[2 * DD];
    const int b = blockIdx.x, d = threadIdx.x;  // 128 threads
    float M = -INFINITY;
#pragma unroll
    for (int j = 0; j < NCHUNK; j++) M = fmaxf(M, Mp[b * NCHUNK + j]);
    float T = 0.f, acc = 0.f;
#pragma unroll
    for (int j = 0; j < NCHUNK; j++) {
        float e = __expf(Mp[b * NCHUNK + j] - M);
        T += Tp[b * NCHUNK + j] * e;
        acc += wcp[(size_t)(b * NCHUNK + j) * DD + d] * e;
    }
    float ti = 1.f / T;
    cat[d] = acc * ti;          // weighted_context
    cat[DD + d] = q[b * DD + d];
    if (d == 0) { Ms[b] = M; Tinv[b] = ti; }
    __syncthreads();
    const float4* wrow = (const float4*)(W_out + (size_t)d * 2 * DD);
    float a2 = 0.f;
#pragma unroll
    for (int k4 = 0; k4 < 2 * DD / 4; k4++) {
        float4 w = wrow[k4];
        float4 x = ((const float4*)cat)[k4];
        a2 += w.x * x.x + w.y * x.y + w.z * x.z + w.w * x.w;
    }
    h[b * DD + d] = tanh_fast(a2);
}

// ---------------- K4: attn = exp(scores - M)/T
__global__ __launch_bounds__(512) void attnfin_kernel(const float* __restrict__ scores,
                                                      const float* __restrict__ Ms,
                                                      const float* __restrict__ Tinv,
                                                      float* __restrict__ attn) {
    const int b = blockIdx.x >> 2, seg = blockIdx.x & 3;
    const float M = Ms[b], ti = Tinv[b];
    const float4* s4 = (const float4*)(scores + (size_t)b * SS) + seg * 512;
    float4* a4 = (float4*)(attn + (size_t)b * SS) + seg * 512;
    float4 v = s4[threadIdx.x];
    v.x = __expf(v.x - M) * ti;
    v.y = __expf(v.y - M) * ti;
    v.z = __expf(v.z - M) * ti;
    v.w = __expf(v.w - M) * ti;
    a4[threadIdx.x] = v;
}

extern "C" void kernel_launch(void* const* d_in, const int* in_sizes, int n_in,
                              void* d_out, int out_size, void* d_ws, size_t ws_size,
                              hipStream_t stream) {
    const float* input = (const float*)d_in[0];
    const float* ctx   = (const float*)d_in[1];
    const float* W_enc = (const float*)d_in[2];
    const float* b_enc = (const float*)d_in[3];
    const float* W_dec = (const float*)d_in[4];
    const float* b_dec = (const float*)d_in[5];
    const float* W_out = (const float*)d_in[6];

    float* h    = (float*)d_out;            // [B, D]
    float* attn = (float*)d_out + BB * DD;  // [B, S]

    float* ws     = (float*)d_ws;
    float* q      = ws;                       // 8192
    float* scores = ws + 8192;                // 524288 raw scores
    float* wcp    = scores + 524288;          // 512*128 partials
    float* Mp     = wcp + 512 * DD;           // 512
    float* Tp     = Mp + 512;                 // 512
    float* Ms     = Tp + 512;                 // 64
    float* Tinv   = Ms + 64;                  // 64

    qproj_kernel<<<BB, DD, 0, stream>>>(input, W_dec, b_dec, q);
    score_fused_kernel<<<BB * NCHUNK, 256, 0, stream>>>(ctx, W_enc, b_enc, q,
                                                        scores, wcp, Mp, Tp);
    combine_out_kernel<<<BB, DD, 0, stream>>>(wcp, Mp, Tp, q, W_out, h, Ms, Tinv);
    attnfin_kernel<<<BB * 4, 512, 0, stream>>>(scores, Ms, Tinv, attn);
}